// Round 4
// baseline (1652.180 us; speedup 1.0000x reference)
//
#include <hip/hip_runtime.h>
#include <math.h>

// Problem constants
#define BG 1024
#define EPG 512
#define ETOT (BG*EPG)
#define DIM 512
#define KP1 52
#define KP2 42
#define KP3 34

typedef unsigned int uint;
typedef short s16x8 __attribute__((ext_vector_type(8)));
typedef float f32x4 __attribute__((ext_vector_type(4)));

// ---------------- bf16 split helpers ----------------
__device__ __forceinline__ unsigned short f2b(float x) {
    uint u = __float_as_uint(x);
    u = u + 0x7fffu + ((u >> 16) & 1u);
    return (unsigned short)(u >> 16);
}
__device__ __forceinline__ float b2f(unsigned short h) {
    return __uint_as_float(((uint)h) << 16);
}
__device__ __forceinline__ void splitf(float x, unsigned short& h, unsigned short& l) {
    h = f2b(x);
    l = f2b(x - b2f(h));
}
__device__ __forceinline__ uint pk2(unsigned short a, unsigned short b) {
    return (uint)a | ((uint)b << 16);
}

// ---------------------------------------------------------------------------
// 1. Gather + split: X[i,:] = emb[ids[i],:]  ->  hi/lo bf16 planes
// ---------------------------------------------------------------------------
__global__ void __launch_bounds__(256)
gather_split(const int* __restrict__ ids, const float* __restrict__ emb,
             unsigned short* __restrict__ Xhi, unsigned short* __restrict__ Xlo)
{
    int tid = blockIdx.x * 256 + threadIdx.x;    // rows*64, 8 elems each
    int row = tid >> 6;
    int c8  = (tid & 63) * 8;
    const float4* s = (const float4*)(emb + (size_t)ids[row] * DIM + c8);
    float4 v0 = s[0], v1 = s[1];
    float vs[8] = {v0.x,v0.y,v0.z,v0.w,v1.x,v1.y,v1.z,v1.w};
    unsigned short h[8], l[8];
#pragma unroll
    for (int i = 0; i < 8; ++i) splitf(vs[i], h[i], l[i]);
    uint4 H, L;
    H.x = pk2(h[0],h[1]); H.y = pk2(h[2],h[3]); H.z = pk2(h[4],h[5]); H.w = pk2(h[6],h[7]);
    L.x = pk2(l[0],l[1]); L.y = pk2(l[2],l[3]); L.z = pk2(l[4],l[5]); L.w = pk2(l[6],l[7]);
    *(uint4*)(Xhi + (size_t)row * DIM + c8) = H;
    *(uint4*)(Xlo + (size_t)row * DIM + c8) = L;
}

// ---------------------------------------------------------------------------
// 2. Weight convert, all 6 weights in one launch
// ---------------------------------------------------------------------------
struct WPtrs { const float* w[6]; };

__global__ void __launch_bounds__(256)
split_wT_all(WPtrs p, unsigned short* __restrict__ WT)
{
    const int wi = blockIdx.x >> 8;
    const int bb = blockIdx.x & 255;
    const float* W = p.w[wi];
    unsigned short* Thi = WT + (size_t)(2 * wi) * DIM * DIM;
    unsigned short* Tlo = Thi + (size_t)DIM * DIM;
    __shared__ float tl[32][33];
    const int t  = threadIdx.x;
    const int bx = bb & 15;   // n-tile
    const int by = bb >> 4;   // k-tile
    const int lx = t & 31, ly = t >> 5;
    for (int r = ly; r < 32; r += 8)
        tl[r][lx] = W[(size_t)(by*32 + r) * DIM + bx*32 + lx];
    __syncthreads();
    for (int r = ly; r < 32; r += 8) {
        float v = tl[lx][r];
        unsigned short h, l; splitf(v, h, l);
        size_t o = (size_t)(bx*32 + r) * DIM + by*32 + lx;
        Thi[o] = h; Tlo[o] = l;
    }
}

// ---------------------------------------------------------------------------
// 3. Mean aggregation with LDS-staged node block (8x global-traffic cut).
//    Each graph's NPER rows (hi+lo) staged to LDS once (<=128 KB), then the
//    512-edge accumulation reads LDS. Deterministic counting sort as before.
// ---------------------------------------------------------------------------
template<int NPER>
__global__ void __launch_bounds__(256)
agg_lds(const unsigned short* __restrict__ Xhi, const unsigned short* __restrict__ Xlo,
        const int* __restrict__ esrc, const int* __restrict__ edst,
        const float* __restrict__ emask,
        unsigned short* __restrict__ Ghi, unsigned short* __restrict__ Glo)
{
    const int g = blockIdx.x;
    const int t = threadIdx.x;
    // row layout: xs[row*1024 + 0..511] = hi, xs[row*1024 + 512..1023] = lo
    __shared__ __align__(16) unsigned short xs[NPER * 1024];
    __shared__ int ldst[EPG];
    __shared__ int ssrc[EPG];
    __shared__ int cnt4[4][64];
    __shared__ int offs[NPER + 1];
    __shared__ int lsrc[EPG];

    // ---- stage node rows: NPER*128 uint4 slots ----
    for (int s = t; s < NPER * 128; s += 256) {
        const int row  = s >> 7;
        const int half = (s >> 6) & 1;          // 0 = hi, 1 = lo
        const int c8   = (s & 63) * 8;
        const unsigned short* src =
            (half ? Xlo : Xhi) + (size_t)(g * NPER + row) * DIM + c8;
        ((uint4*)xs)[s] = *(const uint4*)src;
    }
    // ---- stage edges ----
    const int eb = g * EPG;
    for (int e = t; e < EPG; e += 256) {
        float m = emask ? emask[eb + e] : 1.0f;
        ldst[e] = (m > 0.f) ? (edst[eb + e] - g * NPER) : -1;
        lsrc[e] = esrc[eb + e] - g * NPER;
    }
    __syncthreads();
    {   // quartered counting (deterministic)
        const int d = t & 63, q = t >> 6;
        int c = 0;
        for (int e = q * 128; e < q * 128 + 128; ++e) c += (ldst[e] == d);
        cnt4[q][d] = c;
    }
    __syncthreads();
    if (t == 0) {
        int s = 0;
        for (int i = 0; i < NPER; ++i) {
            offs[i] = s;
            s += cnt4[0][i] + cnt4[1][i] + cnt4[2][i] + cnt4[3][i];
        }
        offs[NPER] = s;
    }
    __syncthreads();
    {   // ordered insertion (edge order preserved)
        const int d = t & 63, q = t >> 6;
        if (d < NPER) {
            int w = offs[d];
            for (int q2 = 0; q2 < q; ++q2) w += cnt4[q2][d];
            for (int e = q * 128; e < q * 128 + 128; ++e)
                if (ldst[e] == d) ssrc[w++] = lsrc[e];
        }
    }
    __syncthreads();
    // ---- accumulate from LDS ----
    const int ch = (t & 127) * 4;               // dim chunk
    const int d0 = t >> 7;                      // 0 or 1
    for (int d = d0; d < NPER; d += 2) {
        const int c0 = offs[d], c1 = offs[d + 1];
        float s0 = 0.f, s1 = 0.f, s2 = 0.f, s3 = 0.f;
        for (int j = c0; j < c1; ++j) {
            const int base = ssrc[j] * 1024 + ch;
            ushort4 h = *(const ushort4*)&xs[base];
            ushort4 l = *(const ushort4*)&xs[base + 512];
            s0 += b2f(h.x) + b2f(l.x);
            s1 += b2f(h.y) + b2f(l.y);
            s2 += b2f(h.z) + b2f(l.z);
            s3 += b2f(h.w) + b2f(l.w);
        }
        const float den = fmaxf((float)(c1 - c0), 1.0f);
        s0 /= den; s1 /= den; s2 /= den; s3 /= den;
        unsigned short h0,h1,h2,h3,l0,l1,l2,l3;
        splitf(s0,h0,l0); splitf(s1,h1,l1); splitf(s2,h2,l2); splitf(s3,h3,l3);
        const size_t wo = (size_t)(g * NPER + d) * DIM + ch;
        *(uint2*)(Ghi + wo) = make_uint2(pk2(h0,h1), pk2(h2,h3));
        *(uint2*)(Glo + wo) = make_uint2(pk2(l0,l1), pk2(l2,l3));
    }
}

// ---------------------------------------------------------------------------
// 4. Split-bf16 MFMA GEMM (unchanged; at m97-structure ceiling)
// ---------------------------------------------------------------------------
__device__ __forceinline__ void gload16(const void* g, void* l) {
    __builtin_amdgcn_global_load_lds(
        (const __attribute__((address_space(1))) void*)g,
        (__attribute__((address_space(3))) void*)l, 16, 0, 0);
}

__global__ void __launch_bounds__(256)
gemm_sage(const unsigned short* __restrict__ Ghi, const unsigned short* __restrict__ Glo,
          const unsigned short* __restrict__ WLhi, const unsigned short* __restrict__ WLlo,
          const unsigned short* __restrict__ Xhi, const unsigned short* __restrict__ Xlo,
          const unsigned short* __restrict__ WRhi, const unsigned short* __restrict__ WRlo,
          const float* __restrict__ bias, float* __restrict__ C, int M)
{
    __shared__ unsigned short sA[128 * 64];
    __shared__ unsigned short sW[128 * 64];

    const int t = threadIdx.x;
    const uint nwg = gridDim.x;
    const uint q8  = nwg >> 3;
    const uint bid = blockIdx.x;
    const uint sw  = (bid & 7) * q8 + (bid >> 3);
    const int  m0  = (int)(sw >> 2) * 128;
    const int  n0  = (int)(sw & 3) * 128;

    const int l  = t & 63;
    const int w  = t >> 6;
    const int wr = w >> 1;
    const int wc = w & 1;
    const int lr = l & 15;
    const int lq = l >> 4;

    f32x4 acc[4][4];
#pragma unroll
    for (int i = 0; i < 4; ++i)
#pragma unroll
        for (int j = 0; j < 4; ++j) acc[i][j] = (f32x4){0.f, 0.f, 0.f, 0.f};

    uint srow[4], soff[4];
#pragma unroll
    for (int i = 0; i < 4; ++i) {
        uint p = (uint)i * 256u + (uint)t;
        uint row = p >> 3, pc = p & 7;
        srow[i] = row;
        soff[i] = (pc ^ (row & 7u)) * 8u;
    }

#pragma unroll 1
    for (int s = 0; s < 6; ++s) {
        const int src = (s >= 3) ? 1 : 0;
        const int combo = s - src * 3;               // 0 hh, 1 hl, 2 lh
        const unsigned short* Ap = src ? ((combo == 2) ? Xlo : Xhi)
                                       : ((combo == 2) ? Glo : Ghi);
        const unsigned short* Wp = src ? ((combo == 1) ? WRlo : WRhi)
                                       : ((combo == 1) ? WLlo : WLhi);
#pragma unroll 1
        for (int kt = 0; kt < 8; ++kt) {
            const int kb = kt * 64;
#pragma unroll
            for (int i = 0; i < 4; ++i) {
                const unsigned short* ga =
                    Ap + (size_t)(m0 + srow[i]) * DIM + kb + soff[i];
                const unsigned short* gw =
                    Wp + (size_t)(n0 + srow[i]) * DIM + kb + soff[i];
                uint p16 = ((uint)i * 256u + (uint)t) * 16u;
                gload16(ga, (char*)sA + p16);
                gload16(gw, (char*)sW + p16);
            }
            __syncthreads();
#pragma unroll
            for (int ks = 0; ks < 2; ++ks) {
                s16x8 af[4], wf[4];
#pragma unroll
                for (int i = 0; i < 4; ++i) {
                    int arow = wr * 64 + i * 16 + lr;
                    int off = arow * 128 + 16 * ((ks * 4 + lq) ^ (arow & 7));
                    af[i] = *(const s16x8*)((const char*)sA + off);
                }
#pragma unroll
                for (int j = 0; j < 4; ++j) {
                    int wrow = wc * 64 + j * 16 + lr;
                    int off = wrow * 128 + 16 * ((ks * 4 + lq) ^ (wrow & 7));
                    wf[j] = *(const s16x8*)((const char*)sW + off);
                }
#pragma unroll
                for (int i = 0; i < 4; ++i)
#pragma unroll
                    for (int j = 0; j < 4; ++j)
                        acc[i][j] = __builtin_amdgcn_mfma_f32_16x16x32_bf16(
                            af[i], wf[j], acc[i][j], 0, 0, 0);
            }
            __syncthreads();
        }
    }

#pragma unroll
    for (int i = 0; i < 4; ++i) {
        const int r0 = m0 + wr * 64 + i * 16 + lq * 4;
#pragma unroll
        for (int j = 0; j < 4; ++j) {
            const int cc = n0 + wc * 64 + j * 16 + lr;
            const float bv = bias[cc];
#pragma unroll
            for (int r = 0; r < 4; ++r) {
                float v = acc[i][j][r] + bv;
                C[(size_t)(r0 + r) * DIM + cc] = fmaxf(v, 0.f);
            }
        }
    }
}

// ---------------------------------------------------------------------------
// 5. TopK pooling: rank in fp32, gate, write split planes
// ---------------------------------------------------------------------------
template<int NPER, int KEEP>
__global__ void __launch_bounds__(256)
topk_split(const float* __restrict__ Y, const float* __restrict__ p,
           unsigned short* __restrict__ Xhi, unsigned short* __restrict__ Xlo,
           int* __restrict__ newid)
{
    const int g = blockIdx.x;
    const int t = threadIdx.x;
    const int wave = t >> 6, lane = t & 63;
    __shared__ float ssc[NPER];
    __shared__ float spnorm;
    __shared__ int   perm[KEEP];
    __shared__ float sgate[KEEP];

    if (wave == 0) {
        float v = 0.f;
#pragma unroll
        for (int i = 0; i < 8; ++i) { float x = p[lane + i * 64]; v = fmaf(x, x, v); }
#pragma unroll
        for (int off = 32; off; off >>= 1) v += __shfl_down(v, off);
        if (lane == 0) spnorm = sqrtf(v);
    }
    for (int nl = wave; nl < NPER; nl += 4) {
        const float* yr = Y + (size_t)(g * NPER + nl) * DIM;
        float v = 0.f;
#pragma unroll
        for (int i = 0; i < 8; ++i) v = fmaf(yr[lane + i * 64], p[lane + i * 64], v);
#pragma unroll
        for (int off = 32; off; off >>= 1) v += __shfl_down(v, off);
        if (lane == 0) ssc[nl] = v;
    }
    __syncthreads();
    float s = 0.f;
    if (t < NPER) s = tanhf(ssc[t] / spnorm);
    __syncthreads();
    if (t < NPER) ssc[t] = s;
    __syncthreads();
    if (t < NPER) {
        int r = 0;
        for (int j = 0; j < NPER; ++j) {
            float sj = ssc[j];
            r += (sj > s) || (sj == s && j < t);
        }
        newid[g * NPER + t] = (r < KEEP) ? (g * KEEP + r) : -1;
        if (r < KEEP) { perm[r] = t; sgate[r] = s; }
    }
    __syncthreads();
    for (int r = 0; r < KEEP; ++r) {
        const float2* src = (const float2*)(Y + (size_t)(g * NPER + perm[r]) * DIM);
        const float sv = sgate[r];
        float2 v = src[t];
        float a = v.x * sv, b = v.y * sv;
        unsigned short ha, la, hb, lb;
        splitf(a, ha, la); splitf(b, hb, lb);
        size_t o = (size_t)(g * KEEP + r) * DIM + 2 * t;
        *(uint*)(Xhi + o) = pk2(ha, hb);
        *(uint*)(Xlo + o) = pk2(la, lb);
    }
}

// ---------------------------------------------------------------------------
// 6. Edge remap after pooling
// ---------------------------------------------------------------------------
__global__ void __launch_bounds__(256)
remap_kernel(const int* __restrict__ es, const int* __restrict__ ed,
             const float* __restrict__ em, const int* __restrict__ newid,
             int* __restrict__ nes, int* __restrict__ ned, float* __restrict__ nem)
{
    int e = blockIdx.x * 256 + threadIdx.x;
    if (e >= ETOT) return;
    float m = em ? em[e] : 1.f;
    int s = newid[es[e]];
    int d = newid[ed[e]];
    bool v = (m > 0.f) && (s >= 0) && (d >= 0);
    nes[e] = v ? s : 0;
    ned[e] = v ? d : 0;
    nem[e] = v ? 1.f : 0.f;
}

// ---------------------------------------------------------------------------
// 7. Readout from split planes
// ---------------------------------------------------------------------------
__global__ void __launch_bounds__(256)
readout_split(const unsigned short* __restrict__ Xhi, const unsigned short* __restrict__ Xlo,
              float* __restrict__ H, int keep, int init)
{
    const int g = blockIdx.x;
    const int t = threadIdx.x;
    for (int c = t; c < DIM; c += 256) {
        float mx = -1e30f, sm = 0.f;
        for (int r = 0; r < keep; ++r) {
            size_t o = (size_t)(g * keep + r) * DIM + c;
            float v = b2f(Xhi[o]) + b2f(Xlo[o]);
            mx = fmaxf(mx, v); sm += v;
        }
        float mean = sm / (float)keep;
        size_t o = (size_t)g * 1024;
        if (init) { H[o + c] = mx;  H[o + 512 + c] = mean; }
        else      { H[o + c] += mx; H[o + 512 + c] += mean; }
    }
}

// ---------------------------------------------------------------------------
// 8. Fused MLP head: out = sigmoid(relu-chain(H) @ ... ), 2 rows per block
// ---------------------------------------------------------------------------
__global__ void __launch_bounds__(256)
mlp_fused(const float* __restrict__ H,
          const float* __restrict__ lw1, const float* __restrict__ lb1,
          const float* __restrict__ lw2, const float* __restrict__ lb2,
          const float* __restrict__ lw3, const float* __restrict__ lb3,
          const float* __restrict__ lw4, const float* __restrict__ lb4,
          const float* __restrict__ lw5, const float* __restrict__ lb5,
          float* __restrict__ out)
{
    __shared__ float h0[2][1024];
    __shared__ float y1[2][512];
    __shared__ float y2[2][256];
    __shared__ float y3[2][128];
    __shared__ float y4[2][64];
    const int t = threadIdx.x;
    const int r0 = blockIdx.x * 2;

    {
        float4 a = *(const float4*)&H[(size_t)r0 * 1024 + t * 4];
        float4 b = *(const float4*)&H[(size_t)(r0 + 1) * 1024 + t * 4];
        *(float4*)&h0[0][t * 4] = a;
        *(float4*)&h0[1][t * 4] = b;
    }
    __syncthreads();
    // layer 1: 1024 -> 512
    {
        float a00 = 0.f, a01 = 0.f, a10 = 0.f, a11 = 0.f;
        const int c = t * 2;
#pragma unroll 4
        for (int k = 0; k < 1024; ++k) {
            float2 wv = *(const float2*)&lw1[(size_t)k * 512 + c];
            float x0 = h0[0][k], x1 = h0[1][k];
            a00 = fmaf(x0, wv.x, a00); a01 = fmaf(x0, wv.y, a01);
            a10 = fmaf(x1, wv.x, a10); a11 = fmaf(x1, wv.y, a11);
        }
        y1[0][c]     = fmaxf(a00 + lb1[c], 0.f);
        y1[0][c + 1] = fmaxf(a01 + lb1[c + 1], 0.f);
        y1[1][c]     = fmaxf(a10 + lb1[c], 0.f);
        y1[1][c + 1] = fmaxf(a11 + lb1[c + 1], 0.f);
    }
    __syncthreads();
    // layer 2: 512 -> 256
    {
        float a0 = 0.f, a1 = 0.f;
#pragma unroll 4
        for (int k = 0; k < 512; ++k) {
            float wv = lw2[(size_t)k * 256 + t];
            a0 = fmaf(y1[0][k], wv, a0);
            a1 = fmaf(y1[1][k], wv, a1);
        }
        y2[0][t] = fmaxf(a0 + lb2[t], 0.f);
        y2[1][t] = fmaxf(a1 + lb2[t], 0.f);
    }
    __syncthreads();
    // layer 3: 256 -> 128
    if (t < 128) {
        float a0 = 0.f, a1 = 0.f;
#pragma unroll 4
        for (int k = 0; k < 256; ++k) {
            float wv = lw3[(size_t)k * 128 + t];
            a0 = fmaf(y2[0][k], wv, a0);
            a1 = fmaf(y2[1][k], wv, a1);
        }
        y3[0][t] = fmaxf(a0 + lb3[t], 0.f);
        y3[1][t] = fmaxf(a1 + lb3[t], 0.f);
    }
    __syncthreads();
    // layer 4: 128 -> 64
    if (t < 64) {
        float a0 = 0.f, a1 = 0.f;
#pragma unroll 4
        for (int k = 0; k < 128; ++k) {
            float wv = lw4[(size_t)k * 64 + t];
            a0 = fmaf(y3[0][k], wv, a0);
            a1 = fmaf(y3[1][k], wv, a1);
        }
        y4[0][t] = fmaxf(a0 + lb4[t], 0.f);
        y4[1][t] = fmaxf(a1 + lb4[t], 0.f);
    }
    __syncthreads();
    // layer 5: 64 -> 1
    const int wv = t >> 6, ln = t & 63;
    if (wv < 2) {
        float v = y4[wv][ln] * lw5[ln];
#pragma unroll
        for (int off = 32; off; off >>= 1) v += __shfl_down(v, off);
        if (ln == 0) out[r0 + wv] = 1.f / (1.f + expf(-(v + lb5[0])));
    }
}

// ---------------------------------------------------------------------------
extern "C" void kernel_launch(void* const* d_in, const int* in_sizes, int n_in,
                              void* d_out, int out_size, void* d_ws, size_t ws_size,
                              hipStream_t stream)
{
    const int*   x_ids = (const int*)d_in[0];
    const int*   esrc  = (const int*)d_in[1];
    const int*   edst  = (const int*)d_in[2];
    const float* emb   = (const float*)d_in[3];
    const float* w1l = (const float*)d_in[4],  *b1l = (const float*)d_in[5],  *w1r = (const float*)d_in[6];
    const float* w2l = (const float*)d_in[7],  *b2l = (const float*)d_in[8],  *w2r = (const float*)d_in[9];
    const float* w3l = (const float*)d_in[10], *b3l = (const float*)d_in[11], *w3r = (const float*)d_in[12];
    const float* p1  = (const float*)d_in[13];
    const float* p2  = (const float*)d_in[14];
    const float* p3  = (const float*)d_in[15];
    const float* lw1 = (const float*)d_in[16], *lb1 = (const float*)d_in[17];
    const float* lw2 = (const float*)d_in[18], *lb2 = (const float*)d_in[19];
    const float* lw3 = (const float*)d_in[20], *lb3 = (const float*)d_in[21];
    const float* lw4 = (const float*)d_in[22], *lb4 = (const float*)d_in[23];
    const float* lw5 = (const float*)d_in[24], *lb5 = (const float*)d_in[25];
    float* out = (float*)d_out;

    // ---- workspace layout ----
    const size_t PL = (size_t)65536 * DIM;
    unsigned short* Xhi = (unsigned short*)d_ws;
    unsigned short* Xlo = Xhi + PL;
    unsigned short* Ghi = Xlo + PL;
    unsigned short* Glo = Ghi + PL;
    float* Cc = (float*)(Glo + PL);
    float* H  = Cc + PL;
    int* newid = (int*)(H + (size_t)1024 * 1024);
    int*   ES2 = newid + 65536;
    int*   ED2 = ES2 + ETOT;
    float* EM2 = (float*)(ED2 + ETOT);
    int*   ES3 = (int*)(EM2 + ETOT);
    int*   ED3 = ES3 + ETOT;
    float* EM3 = (float*)(ED3 + ETOT);
    unsigned short* WT = (unsigned short*)(EM3 + ETOT);  // 12 planes x 512*512
    const size_t WSZ = (size_t)DIM * DIM;
    unsigned short *w1lh = WT + 0*WSZ,  *w1ll = WT + 1*WSZ;
    unsigned short *w1rh = WT + 2*WSZ,  *w1rl = WT + 3*WSZ;
    unsigned short *w2lh = WT + 4*WSZ,  *w2ll = WT + 5*WSZ;
    unsigned short *w2rh = WT + 6*WSZ,  *w2rl = WT + 7*WSZ;
    unsigned short *w3lh = WT + 8*WSZ,  *w3ll = WT + 9*WSZ;
    unsigned short *w3rh = WT + 10*WSZ, *w3rl = WT + 11*WSZ;

    // ---- weight conversion (one launch) ----
    WPtrs wp;
    wp.w[0] = w1l; wp.w[1] = w1r; wp.w[2] = w2l;
    wp.w[3] = w2r; wp.w[4] = w3l; wp.w[5] = w3r;
    split_wT_all<<<6 * 256, 256, 0, stream>>>(wp, WT);

    // ---- layer 1 ----
    gather_split<<<16384, 256, 0, stream>>>(x_ids, emb, Xhi, Xlo);
    agg_lds<64><<<BG, 256, 0, stream>>>(Xhi, Xlo, esrc, edst, nullptr, Ghi, Glo);
    gemm_sage<<<(65536/128)*4, 256, 0, stream>>>(Ghi, Glo, w1lh, w1ll,
                                                 Xhi, Xlo, w1rh, w1rl, b1l, Cc, 65536);
    topk_split<64, KP1><<<BG, 256, 0, stream>>>(Cc, p1, Xhi, Xlo, newid);
    remap_kernel<<<ETOT/256, 256, 0, stream>>>(esrc, edst, nullptr, newid, ES2, ED2, EM2);
    readout_split<<<BG, 256, 0, stream>>>(Xhi, Xlo, H, KP1, 1);

    // ---- layer 2 ----
    agg_lds<KP1><<<BG, 256, 0, stream>>>(Xhi, Xlo, ES2, ED2, EM2, Ghi, Glo);
    gemm_sage<<<(53248/128)*4, 256, 0, stream>>>(Ghi, Glo, w2lh, w2ll,
                                                 Xhi, Xlo, w2rh, w2rl, b2l, Cc, 53248);
    topk_split<KP1, KP2><<<BG, 256, 0, stream>>>(Cc, p2, Xhi, Xlo, newid);
    remap_kernel<<<ETOT/256, 256, 0, stream>>>(ES2, ED2, EM2, newid, ES3, ED3, EM3);
    readout_split<<<BG, 256, 0, stream>>>(Xhi, Xlo, H, KP2, 0);

    // ---- layer 3 ----
    agg_lds<KP2><<<BG, 256, 0, stream>>>(Xhi, Xlo, ES3, ED3, EM3, Ghi, Glo);
    gemm_sage<<<(43008/128)*4, 256, 0, stream>>>(Ghi, Glo, w3lh, w3ll,
                                                 Xhi, Xlo, w3rh, w3rl, b3l, Cc, 43008);
    topk_split<KP2, KP3><<<BG, 256, 0, stream>>>(Cc, p3, Xhi, Xlo, newid);
    readout_split<<<BG, 256, 0, stream>>>(Xhi, Xlo, H, KP3, 0);

    // ---- fused MLP head ----
    mlp_fused<<<512, 256, 0, stream>>>(H, lw1, lb1, lw2, lb2, lw3, lb3,
                                       lw4, lb4, lw5, lb5, out);
}

// Round 5
// 1388.592 us; speedup vs baseline: 1.1898x; 1.1898x over previous
//
#include <hip/hip_runtime.h>
#include <math.h>

// Problem constants
#define BG 1024
#define EPG 512
#define ETOT (BG*EPG)
#define DIM 512
#define KP1 52
#define KP2 42
#define KP3 34

typedef unsigned int uint;
typedef short s16x8 __attribute__((ext_vector_type(8)));
typedef float f32x4 __attribute__((ext_vector_type(4)));

// ---------------- bf16 split helpers ----------------
__device__ __forceinline__ unsigned short f2b(float x) {
    uint u = __float_as_uint(x);
    u = u + 0x7fffu + ((u >> 16) & 1u);
    return (unsigned short)(u >> 16);
}
__device__ __forceinline__ float b2f(unsigned short h) {
    return __uint_as_float(((uint)h) << 16);
}
__device__ __forceinline__ void splitf(float x, unsigned short& h, unsigned short& l) {
    h = f2b(x);
    l = f2b(x - b2f(h));
}
__device__ __forceinline__ uint pk2(unsigned short a, unsigned short b) {
    return (uint)a | ((uint)b << 16);
}

__device__ __forceinline__ void gload16(const void* g, void* l) {
    __builtin_amdgcn_global_load_lds(
        (const __attribute__((address_space(1))) void*)g,
        (__attribute__((address_space(3))) void*)l, 16, 0, 0);
}

// ---------------------------------------------------------------------------
// 1. Gather + split: X[i,:] = emb[ids[i],:]  ->  hi/lo bf16 planes
// ---------------------------------------------------------------------------
__global__ void __launch_bounds__(256)
gather_split(const int* __restrict__ ids, const float* __restrict__ emb,
             unsigned short* __restrict__ Xhi, unsigned short* __restrict__ Xlo)
{
    int tid = blockIdx.x * 256 + threadIdx.x;    // rows*64, 8 elems each
    int row = tid >> 6;
    int c8  = (tid & 63) * 8;
    const float4* s = (const float4*)(emb + (size_t)ids[row] * DIM + c8);
    float4 v0 = s[0], v1 = s[1];
    float vs[8] = {v0.x,v0.y,v0.z,v0.w,v1.x,v1.y,v1.z,v1.w};
    unsigned short h[8], l[8];
#pragma unroll
    for (int i = 0; i < 8; ++i) splitf(vs[i], h[i], l[i]);
    uint4 H, L;
    H.x = pk2(h[0],h[1]); H.y = pk2(h[2],h[3]); H.z = pk2(h[4],h[5]); H.w = pk2(h[6],h[7]);
    L.x = pk2(l[0],l[1]); L.y = pk2(l[2],l[3]); L.z = pk2(l[4],l[5]); L.w = pk2(l[6],l[7]);
    *(uint4*)(Xhi + (size_t)row * DIM + c8) = H;
    *(uint4*)(Xlo + (size_t)row * DIM + c8) = L;
}

// ---------------------------------------------------------------------------
// 2. Weight convert, all 6 weights in one launch
// ---------------------------------------------------------------------------
struct WPtrs { const float* w[6]; };

__global__ void __launch_bounds__(256)
split_wT_all(WPtrs p, unsigned short* __restrict__ WT)
{
    const int wi = blockIdx.x >> 8;
    const int bb = blockIdx.x & 255;
    const float* W = p.w[wi];
    unsigned short* Thi = WT + (size_t)(2 * wi) * DIM * DIM;
    unsigned short* Tlo = Thi + (size_t)DIM * DIM;
    __shared__ float tl[32][33];
    const int t  = threadIdx.x;
    const int bx = bb & 15;   // n-tile
    const int by = bb >> 4;   // k-tile
    const int lx = t & 31, ly = t >> 5;
    for (int r = ly; r < 32; r += 8)
        tl[r][lx] = W[(size_t)(by*32 + r) * DIM + bx*32 + lx];
    __syncthreads();
    for (int r = ly; r < 32; r += 8) {
        float v = tl[lx][r];
        unsigned short h, l; splitf(v, h, l);
        size_t o = (size_t)(bx*32 + r) * DIM + by*32 + lx;
        Thi[o] = h; Tlo[o] = l;
    }
}

// ---------------------------------------------------------------------------
// 3. Mean aggregation, column-sliced: block = (graph, dim-quarter).
//    LDS stages the graph's node rows for THIS 128-dim slice only (32 KB)
//    -> 4 blocks/CU, 4096 blocks; traffic stays 8x-reduced.
// ---------------------------------------------------------------------------
template<int NPER>
__global__ void __launch_bounds__(256, 4)
agg_lds4(const unsigned short* __restrict__ Xhi, const unsigned short* __restrict__ Xlo,
         const int* __restrict__ esrc, const int* __restrict__ edst,
         const float* __restrict__ emask,
         unsigned short* __restrict__ Ghi, unsigned short* __restrict__ Glo)
{
    const int g  = blockIdx.x >> 2;       // graph
    const int c0 = (blockIdx.x & 3) * 128;  // dim slice base
    const int t  = threadIdx.x;
    // xs[row][half][128] : row stride 256 ushorts (512 B), linear for gload16
    __shared__ __align__(16) unsigned short xs[NPER * 256];
    __shared__ int ldst[EPG];
    __shared__ int lsrc[EPG];
    __shared__ int ssrc[EPG];
    __shared__ int cnt4[4][64];
    __shared__ int offs[NPER + 1];

    // ---- stage node-row slices via global_load_lds (16B/lane, linear dest)
    // slot s: row = s>>5, half = (s>>4)&1, c8 = (s&15)*8
    for (int s = t; s < NPER * 32; s += 256) {
        const int row  = s >> 5;
        const int half = (s >> 4) & 1;
        const int c8   = (s & 15) * 8;
        const unsigned short* src =
            (half ? Xlo : Xhi) + (size_t)(g * NPER + row) * DIM + c0 + c8;
        gload16(src, (char*)xs + (size_t)s * 16);
    }
    // ---- stage edges ----
    const int eb = g * EPG;
    for (int e = t; e < EPG; e += 256) {
        float m = emask ? emask[eb + e] : 1.0f;
        ldst[e] = (m > 0.f) ? (edst[eb + e] - g * NPER) : -1;
        lsrc[e] = esrc[eb + e] - g * NPER;
    }
    __syncthreads();
    {   // quartered counting (deterministic)
        const int d = t & 63, q = t >> 6;
        int c = 0;
        for (int e = q * 128; e < q * 128 + 128; ++e) c += (ldst[e] == d);
        cnt4[q][d] = c;
    }
    __syncthreads();
    if (t == 0) {
        int s = 0;
        for (int i = 0; i < NPER; ++i) {
            offs[i] = s;
            s += cnt4[0][i] + cnt4[1][i] + cnt4[2][i] + cnt4[3][i];
        }
        offs[NPER] = s;
    }
    __syncthreads();
    {   // ordered insertion (edge order preserved)
        const int d = t & 63, q = t >> 6;
        if (d < NPER) {
            int w = offs[d];
            for (int q2 = 0; q2 < q; ++q2) w += cnt4[q2][d];
            for (int e = q * 128; e < q * 128 + 128; ++e)
                if (ldst[e] == d) ssrc[w++] = lsrc[e];
        }
    }
    __syncthreads();
    // ---- accumulate from LDS: thread -> (dst row, 4-dim chunk) ----
    const int ch = (t & 31) * 4;            // within 128-dim slice
    const int d0 = t >> 5;                  // 0..7
    for (int d = d0; d < NPER; d += 8) {
        const int cA = offs[d], cB = offs[d + 1];
        float s0 = 0.f, s1 = 0.f, s2 = 0.f, s3 = 0.f;
        for (int j = cA; j < cB; ++j) {
            const int base = ssrc[j] * 256 + ch;
            ushort4 h = *(const ushort4*)&xs[base];
            ushort4 l = *(const ushort4*)&xs[base + 128];
            s0 += b2f(h.x) + b2f(l.x);
            s1 += b2f(h.y) + b2f(l.y);
            s2 += b2f(h.z) + b2f(l.z);
            s3 += b2f(h.w) + b2f(l.w);
        }
        const float den = fmaxf((float)(cB - cA), 1.0f);
        s0 /= den; s1 /= den; s2 /= den; s3 /= den;
        unsigned short h0,h1,h2,h3,l0,l1,l2,l3;
        splitf(s0,h0,l0); splitf(s1,h1,l1); splitf(s2,h2,l2); splitf(s3,h3,l3);
        const size_t wo = (size_t)(g * NPER + d) * DIM + c0 + ch;
        *(uint2*)(Ghi + wo) = make_uint2(pk2(h0,h1), pk2(h2,h3));
        *(uint2*)(Glo + wo) = make_uint2(pk2(l0,l1), pk2(l2,l3));
    }
}

// ---------------------------------------------------------------------------
// 4. Split-bf16 MFMA GEMM (unchanged; at m97-structure ceiling)
// ---------------------------------------------------------------------------
__global__ void __launch_bounds__(256)
gemm_sage(const unsigned short* __restrict__ Ghi, const unsigned short* __restrict__ Glo,
          const unsigned short* __restrict__ WLhi, const unsigned short* __restrict__ WLlo,
          const unsigned short* __restrict__ Xhi, const unsigned short* __restrict__ Xlo,
          const unsigned short* __restrict__ WRhi, const unsigned short* __restrict__ WRlo,
          const float* __restrict__ bias, float* __restrict__ C, int M)
{
    __shared__ unsigned short sA[128 * 64];
    __shared__ unsigned short sW[128 * 64];

    const int t = threadIdx.x;
    const uint nwg = gridDim.x;
    const uint q8  = nwg >> 3;
    const uint bid = blockIdx.x;
    const uint sw  = (bid & 7) * q8 + (bid >> 3);
    const int  m0  = (int)(sw >> 2) * 128;
    const int  n0  = (int)(sw & 3) * 128;

    const int l  = t & 63;
    const int w  = t >> 6;
    const int wr = w >> 1;
    const int wc = w & 1;
    const int lr = l & 15;
    const int lq = l >> 4;

    f32x4 acc[4][4];
#pragma unroll
    for (int i = 0; i < 4; ++i)
#pragma unroll
        for (int j = 0; j < 4; ++j) acc[i][j] = (f32x4){0.f, 0.f, 0.f, 0.f};

    uint srow[4], soff[4];
#pragma unroll
    for (int i = 0; i < 4; ++i) {
        uint p = (uint)i * 256u + (uint)t;
        uint row = p >> 3, pc = p & 7;
        srow[i] = row;
        soff[i] = (pc ^ (row & 7u)) * 8u;
    }

#pragma unroll 1
    for (int s = 0; s < 6; ++s) {
        const int src = (s >= 3) ? 1 : 0;
        const int combo = s - src * 3;               // 0 hh, 1 hl, 2 lh
        const unsigned short* Ap = src ? ((combo == 2) ? Xlo : Xhi)
                                       : ((combo == 2) ? Glo : Ghi);
        const unsigned short* Wp = src ? ((combo == 1) ? WRlo : WRhi)
                                       : ((combo == 1) ? WLlo : WLhi);
#pragma unroll 1
        for (int kt = 0; kt < 8; ++kt) {
            const int kb = kt * 64;
#pragma unroll
            for (int i = 0; i < 4; ++i) {
                const unsigned short* ga =
                    Ap + (size_t)(m0 + srow[i]) * DIM + kb + soff[i];
                const unsigned short* gw =
                    Wp + (size_t)(n0 + srow[i]) * DIM + kb + soff[i];
                uint p16 = ((uint)i * 256u + (uint)t) * 16u;
                gload16(ga, (char*)sA + p16);
                gload16(gw, (char*)sW + p16);
            }
            __syncthreads();
#pragma unroll
            for (int ks = 0; ks < 2; ++ks) {
                s16x8 af[4], wf[4];
#pragma unroll
                for (int i = 0; i < 4; ++i) {
                    int arow = wr * 64 + i * 16 + lr;
                    int off = arow * 128 + 16 * ((ks * 4 + lq) ^ (arow & 7));
                    af[i] = *(const s16x8*)((const char*)sA + off);
                }
#pragma unroll
                for (int j = 0; j < 4; ++j) {
                    int wrow = wc * 64 + j * 16 + lr;
                    int off = wrow * 128 + 16 * ((ks * 4 + lq) ^ (wrow & 7));
                    wf[j] = *(const s16x8*)((const char*)sW + off);
                }
#pragma unroll
                for (int i = 0; i < 4; ++i)
#pragma unroll
                    for (int j = 0; j < 4; ++j)
                        acc[i][j] = __builtin_amdgcn_mfma_f32_16x16x32_bf16(
                            af[i], wf[j], acc[i][j], 0, 0, 0);
            }
            __syncthreads();
        }
    }

#pragma unroll
    for (int i = 0; i < 4; ++i) {
        const int r0 = m0 + wr * 64 + i * 16 + lq * 4;
#pragma unroll
        for (int j = 0; j < 4; ++j) {
            const int cc = n0 + wc * 64 + j * 16 + lr;
            const float bv = bias[cc];
#pragma unroll
            for (int r = 0; r < 4; ++r) {
                float v = acc[i][j][r] + bv;
                C[(size_t)(r0 + r) * DIM + cc] = fmaxf(v, 0.f);
            }
        }
    }
}

// ---------------------------------------------------------------------------
// 5. TopK pooling: rank in fp32, gate, write split planes
// ---------------------------------------------------------------------------
template<int NPER, int KEEP>
__global__ void __launch_bounds__(256)
topk_split(const float* __restrict__ Y, const float* __restrict__ p,
           unsigned short* __restrict__ Xhi, unsigned short* __restrict__ Xlo,
           int* __restrict__ newid)
{
    const int g = blockIdx.x;
    const int t = threadIdx.x;
    const int wave = t >> 6, lane = t & 63;
    __shared__ float ssc[NPER];
    __shared__ float spnorm;
    __shared__ int   perm[KEEP];
    __shared__ float sgate[KEEP];

    if (wave == 0) {
        float v = 0.f;
#pragma unroll
        for (int i = 0; i < 8; ++i) { float x = p[lane + i * 64]; v = fmaf(x, x, v); }
#pragma unroll
        for (int off = 32; off; off >>= 1) v += __shfl_down(v, off);
        if (lane == 0) spnorm = sqrtf(v);
    }
    for (int nl = wave; nl < NPER; nl += 4) {
        const float* yr = Y + (size_t)(g * NPER + nl) * DIM;
        float v = 0.f;
#pragma unroll
        for (int i = 0; i < 8; ++i) v = fmaf(yr[lane + i * 64], p[lane + i * 64], v);
#pragma unroll
        for (int off = 32; off; off >>= 1) v += __shfl_down(v, off);
        if (lane == 0) ssc[nl] = v;
    }
    __syncthreads();
    float s = 0.f;
    if (t < NPER) s = tanhf(ssc[t] / spnorm);
    __syncthreads();
    if (t < NPER) ssc[t] = s;
    __syncthreads();
    if (t < NPER) {
        int r = 0;
        for (int j = 0; j < NPER; ++j) {
            float sj = ssc[j];
            r += (sj > s) || (sj == s && j < t);
        }
        newid[g * NPER + t] = (r < KEEP) ? (g * KEEP + r) : -1;
        if (r < KEEP) { perm[r] = t; sgate[r] = s; }
    }
    __syncthreads();
    for (int r = 0; r < KEEP; ++r) {
        const float2* src = (const float2*)(Y + (size_t)(g * NPER + perm[r]) * DIM);
        const float sv = sgate[r];
        float2 v = src[t];
        float a = v.x * sv, b = v.y * sv;
        unsigned short ha, la, hb, lb;
        splitf(a, ha, la); splitf(b, hb, lb);
        size_t o = (size_t)(g * KEEP + r) * DIM + 2 * t;
        *(uint*)(Xhi + o) = pk2(ha, hb);
        *(uint*)(Xlo + o) = pk2(la, lb);
    }
}

// ---------------------------------------------------------------------------
// 6. Edge remap after pooling
// ---------------------------------------------------------------------------
__global__ void __launch_bounds__(256)
remap_kernel(const int* __restrict__ es, const int* __restrict__ ed,
             const float* __restrict__ em, const int* __restrict__ newid,
             int* __restrict__ nes, int* __restrict__ ned, float* __restrict__ nem)
{
    int e = blockIdx.x * 256 + threadIdx.x;
    if (e >= ETOT) return;
    float m = em ? em[e] : 1.f;
    int s = newid[es[e]];
    int d = newid[ed[e]];
    bool v = (m > 0.f) && (s >= 0) && (d >= 0);
    nes[e] = v ? s : 0;
    ned[e] = v ? d : 0;
    nem[e] = v ? 1.f : 0.f;
}

// ---------------------------------------------------------------------------
// 7. Readout from split planes
// ---------------------------------------------------------------------------
__global__ void __launch_bounds__(256)
readout_split(const unsigned short* __restrict__ Xhi, const unsigned short* __restrict__ Xlo,
              float* __restrict__ H, int keep, int init)
{
    const int g = blockIdx.x;
    const int t = threadIdx.x;
    for (int c = t; c < DIM; c += 256) {
        float mx = -1e30f, sm = 0.f;
        for (int r = 0; r < keep; ++r) {
            size_t o = (size_t)(g * keep + r) * DIM + c;
            float v = b2f(Xhi[o]) + b2f(Xlo[o]);
            mx = fmaxf(mx, v); sm += v;
        }
        float mean = sm / (float)keep;
        size_t o = (size_t)g * 1024;
        if (init) { H[o + c] = mx;  H[o + 512 + c] = mean; }
        else      { H[o + c] += mx; H[o + 512 + c] += mean; }
    }
}

// ---------------------------------------------------------------------------
// 8. Fused MLP head: out = sigmoid(relu-chain(H) @ ... ), 2 rows per block
// ---------------------------------------------------------------------------
__global__ void __launch_bounds__(256)
mlp_fused(const float* __restrict__ H,
          const float* __restrict__ lw1, const float* __restrict__ lb1,
          const float* __restrict__ lw2, const float* __restrict__ lb2,
          const float* __restrict__ lw3, const float* __restrict__ lb3,
          const float* __restrict__ lw4, const float* __restrict__ lb4,
          const float* __restrict__ lw5, const float* __restrict__ lb5,
          float* __restrict__ out)
{
    __shared__ float h0[2][1024];
    __shared__ float y1[2][512];
    __shared__ float y2[2][256];
    __shared__ float y3[2][128];
    __shared__ float y4[2][64];
    const int t = threadIdx.x;
    const int r0 = blockIdx.x * 2;

    {
        float4 a = *(const float4*)&H[(size_t)r0 * 1024 + t * 4];
        float4 b = *(const float4*)&H[(size_t)(r0 + 1) * 1024 + t * 4];
        *(float4*)&h0[0][t * 4] = a;
        *(float4*)&h0[1][t * 4] = b;
    }
    __syncthreads();
    // layer 1: 1024 -> 512
    {
        float a00 = 0.f, a01 = 0.f, a10 = 0.f, a11 = 0.f;
        const int c = t * 2;
#pragma unroll 4
        for (int k = 0; k < 1024; ++k) {
            float2 wv = *(const float2*)&lw1[(size_t)k * 512 + c];
            float x0 = h0[0][k], x1 = h0[1][k];
            a00 = fmaf(x0, wv.x, a00); a01 = fmaf(x0, wv.y, a01);
            a10 = fmaf(x1, wv.x, a10); a11 = fmaf(x1, wv.y, a11);
        }
        y1[0][c]     = fmaxf(a00 + lb1[c], 0.f);
        y1[0][c + 1] = fmaxf(a01 + lb1[c + 1], 0.f);
        y1[1][c]     = fmaxf(a10 + lb1[c], 0.f);
        y1[1][c + 1] = fmaxf(a11 + lb1[c + 1], 0.f);
    }
    __syncthreads();
    // layer 2: 512 -> 256
    {
        float a0 = 0.f, a1 = 0.f;
#pragma unroll 4
        for (int k = 0; k < 512; ++k) {
            float wv = lw2[(size_t)k * 256 + t];
            a0 = fmaf(y1[0][k], wv, a0);
            a1 = fmaf(y1[1][k], wv, a1);
        }
        y2[0][t] = fmaxf(a0 + lb2[t], 0.f);
        y2[1][t] = fmaxf(a1 + lb2[t], 0.f);
    }
    __syncthreads();
    // layer 3: 256 -> 128
    if (t < 128) {
        float a0 = 0.f, a1 = 0.f;
#pragma unroll 4
        for (int k = 0; k < 256; ++k) {
            float wv = lw3[(size_t)k * 128 + t];
            a0 = fmaf(y2[0][k], wv, a0);
            a1 = fmaf(y2[1][k], wv, a1);
        }
        y3[0][t] = fmaxf(a0 + lb3[t], 0.f);
        y3[1][t] = fmaxf(a1 + lb3[t], 0.f);
    }
    __syncthreads();
    // layer 4: 128 -> 64
    if (t < 64) {
        float a0 = 0.f, a1 = 0.f;
#pragma unroll 4
        for (int k = 0; k < 128; ++k) {
            float wv = lw4[(size_t)k * 64 + t];
            a0 = fmaf(y3[0][k], wv, a0);
            a1 = fmaf(y3[1][k], wv, a1);
        }
        y4[0][t] = fmaxf(a0 + lb4[t], 0.f);
        y4[1][t] = fmaxf(a1 + lb4[t], 0.f);
    }
    __syncthreads();
    // layer 5: 64 -> 1
    const int wv = t >> 6, ln = t & 63;
    if (wv < 2) {
        float v = y4[wv][ln] * lw5[ln];
#pragma unroll
        for (int off = 32; off; off >>= 1) v += __shfl_down(v, off);
        if (ln == 0) out[r0 + wv] = 1.f / (1.f + expf(-(v + lb5[0])));
    }
}

// ---------------------------------------------------------------------------
extern "C" void kernel_launch(void* const* d_in, const int* in_sizes, int n_in,
                              void* d_out, int out_size, void* d_ws, size_t ws_size,
                              hipStream_t stream)
{
    const int*   x_ids = (const int*)d_in[0];
    const int*   esrc  = (const int*)d_in[1];
    const int*   edst  = (const int*)d_in[2];
    const float* emb   = (const float*)d_in[3];
    const float* w1l = (const float*)d_in[4],  *b1l = (const float*)d_in[5],  *w1r = (const float*)d_in[6];
    const float* w2l = (const float*)d_in[7],  *b2l = (const float*)d_in[8],  *w2r = (const float*)d_in[9];
    const float* w3l = (const float*)d_in[10], *b3l = (const float*)d_in[11], *w3r = (const float*)d_in[12];
    const float* p1  = (const float*)d_in[13];
    const float* p2  = (const float*)d_in[14];
    const float* p3  = (const float*)d_in[15];
    const float* lw1 = (const float*)d_in[16], *lb1 = (const float*)d_in[17];
    const float* lw2 = (const float*)d_in[18], *lb2 = (const float*)d_in[19];
    const float* lw3 = (const float*)d_in[20], *lb3 = (const float*)d_in[21];
    const float* lw4 = (const float*)d_in[22], *lb4 = (const float*)d_in[23];
    const float* lw5 = (const float*)d_in[24], *lb5 = (const float*)d_in[25];
    float* out = (float*)d_out;

    // ---- workspace layout ----
    const size_t PL = (size_t)65536 * DIM;
    unsigned short* Xhi = (unsigned short*)d_ws;
    unsigned short* Xlo = Xhi + PL;
    unsigned short* Ghi = Xlo + PL;
    unsigned short* Glo = Ghi + PL;
    float* Cc = (float*)(Glo + PL);
    float* H  = Cc + PL;
    int* newid = (int*)(H + (size_t)1024 * 1024);
    int*   ES2 = newid + 65536;
    int*   ED2 = ES2 + ETOT;
    float* EM2 = (float*)(ED2 + ETOT);
    int*   ES3 = (int*)(EM2 + ETOT);
    int*   ED3 = ES3 + ETOT;
    float* EM3 = (float*)(ED3 + ETOT);
    unsigned short* WT = (unsigned short*)(EM3 + ETOT);  // 12 planes x 512*512
    const size_t WSZ = (size_t)DIM * DIM;
    unsigned short *w1lh = WT + 0*WSZ,  *w1ll = WT + 1*WSZ;
    unsigned short *w1rh = WT + 2*WSZ,  *w1rl = WT + 3*WSZ;
    unsigned short *w2lh = WT + 4*WSZ,  *w2ll = WT + 5*WSZ;
    unsigned short *w2rh = WT + 6*WSZ,  *w2rl = WT + 7*WSZ;
    unsigned short *w3lh = WT + 8*WSZ,  *w3ll = WT + 9*WSZ;
    unsigned short *w3rh = WT + 10*WSZ, *w3rl = WT + 11*WSZ;

    // ---- weight conversion (one launch) ----
    WPtrs wp;
    wp.w[0] = w1l; wp.w[1] = w1r; wp.w[2] = w2l;
    wp.w[3] = w2r; wp.w[4] = w3l; wp.w[5] = w3r;
    split_wT_all<<<6 * 256, 256, 0, stream>>>(wp, WT);

    // ---- layer 1 ----
    gather_split<<<16384, 256, 0, stream>>>(x_ids, emb, Xhi, Xlo);
    agg_lds4<64><<<BG * 4, 256, 0, stream>>>(Xhi, Xlo, esrc, edst, nullptr, Ghi, Glo);
    gemm_sage<<<(65536/128)*4, 256, 0, stream>>>(Ghi, Glo, w1lh, w1ll,
                                                 Xhi, Xlo, w1rh, w1rl, b1l, Cc, 65536);
    topk_split<64, KP1><<<BG, 256, 0, stream>>>(Cc, p1, Xhi, Xlo, newid);
    remap_kernel<<<ETOT/256, 256, 0, stream>>>(esrc, edst, nullptr, newid, ES2, ED2, EM2);
    readout_split<<<BG, 256, 0, stream>>>(Xhi, Xlo, H, KP1, 1);

    // ---- layer 2 ----
    agg_lds4<KP1><<<BG * 4, 256, 0, stream>>>(Xhi, Xlo, ES2, ED2, EM2, Ghi, Glo);
    gemm_sage<<<(53248/128)*4, 256, 0, stream>>>(Ghi, Glo, w2lh, w2ll,
                                                 Xhi, Xlo, w2rh, w2rl, b2l, Cc, 53248);
    topk_split<KP1, KP2><<<BG, 256, 0, stream>>>(Cc, p2, Xhi, Xlo, newid);
    remap_kernel<<<ETOT/256, 256, 0, stream>>>(ES2, ED2, EM2, newid, ES3, ED3, EM3);
    readout_split<<<BG, 256, 0, stream>>>(Xhi, Xlo, H, KP2, 0);

    // ---- layer 3 ----
    agg_lds4<KP2><<<BG * 4, 256, 0, stream>>>(Xhi, Xlo, ES3, ED3, EM3, Ghi, Glo);
    gemm_sage<<<(43008/128)*4, 256, 0, stream>>>(Ghi, Glo, w3lh, w3ll,
                                                 Xhi, Xlo, w3rh, w3rl, b3l, Cc, 43008);
    topk_split<KP2, KP3><<<BG, 256, 0, stream>>>(Cc, p3, Xhi, Xlo, newid);
    readout_split<<<BG, 256, 0, stream>>>(Xhi, Xlo, H, KP3, 0);

    // ---- fused MLP head ----
    mlp_fused<<<512, 256, 0, stream>>>(H, lw1, lb1, lw2, lb2, lw3, lb3,
                                       lw4, lb4, lw5, lb5, out);
}